// Round 4
// baseline (321.234 us; speedup 1.0000x reference)
//
#include <hip/hip_runtime.h>

#define D      128
#define S      10
#define ROWS   64
#define HS     260          // padded LDS row stride (2D=256, +4 keeps 16B align)
#define BLOCK  256

// ---------------- K1: neighbor mean-aggregate -> ws[B][D] ----------------
// One thread per (row, float4-chunk). 10 independent gathers, no LDS, no barriers.
__global__ __launch_bounds__(BLOCK) void mean_kernel(
    const int* __restrict__ neigh, const float* __restrict__ Z,
    float* __restrict__ ws, int B)
{
    const int t = blockIdx.x * BLOCK + threadIdx.x;
    if (t >= B * 32) return;
    const int r = t >> 5;             // batch row
    const int c = t & 31;             // float4 chunk (32 * 16B = 512B row)
    const int* nr = neigh + (size_t)r * S;

    float ax = 0.f, ay = 0.f, az = 0.f, aw = 0.f;
    #pragma unroll
    for (int s = 0; s < S; ++s) {
        const float4 v = ((const float4*)(Z + (size_t)nr[s] * D))[c];
        ax += v.x; ay += v.y; az += v.z; aw += v.w;
    }
    float4 m; m.x = ax * 0.1f; m.y = ay * 0.1f; m.z = az * 0.1f; m.w = aw * 0.1f;
    ((float4*)(ws + (size_t)r * D))[c] = m;
}

// ---------------- K2: self-gather + GEMM + sigmoid + L2-norm ----------------
// R1's proven structure; neighbor loop replaced by a coalesced ws read.
__global__ __launch_bounds__(BLOCK, 2) void sage_gemm_kernel(
    const int* __restrict__ batch, const float* __restrict__ Z,
    const float* __restrict__ ws, const float* __restrict__ W,
    float* __restrict__ out, int B)
{
    __shared__ float Hs[ROWS * HS];       // 66,560 B
    __shared__ int   sb[ROWS];

    const int tid  = threadIdx.x;
    const int base = blockIdx.x * ROWS;
    const int rows = min(ROWS, B - base);

    for (int x = tid; x < rows; x += BLOCK) sb[x] = batch[base + x];
    __syncthreads();

    #pragma unroll
    for (int w = 0; w < (ROWS * 32) / BLOCK; ++w) {   // 8 iterations
        const int task = w * BLOCK + tid;
        const int r = task >> 5;
        const int c = task & 31;
        if (r < rows) {
            const float4 sv = ((const float4*)(Z  + (size_t)sb[r] * D))[c];
            const float4 mv = ((const float4*)(ws + (size_t)(base + r) * D))[c];
            *(float4*)&Hs[r * HS + c * 4]     = sv;
            *(float4*)&Hs[r * HS + D + c * 4] = mv;
        } else {
            const float4 zz = {0.f, 0.f, 0.f, 0.f};
            *(float4*)&Hs[r * HS + c * 4]     = zz;
            *(float4*)&Hs[r * HS + D + c * 4] = zz;
        }
    }
    __syncthreads();

    const int jg = tid & 31;              // 32 column groups x 4 cols
    const int rg = tid >> 5;              // 8 row groups x 8 rows
    const int j0 = jg * 4;

    float acc[8][4];
    #pragma unroll
    for (int i = 0; i < 8; ++i)
        #pragma unroll
        for (int j = 0; j < 4; ++j) acc[i][j] = 0.f;

    for (int k4 = 0; k4 < (2 * D) / 4; ++k4) {
        const int k = k4 * 4;
        float4 wv[4];
        #pragma unroll
        for (int ji = 0; ji < 4; ++ji)
            wv[ji] = *(const float4*)(W + (size_t)(j0 + ji) * (2 * D) + k);
        #pragma unroll
        for (int ri = 0; ri < 8; ++ri) {
            const float4 hv = *(const float4*)&Hs[(rg * 8 + ri) * HS + k];
            #pragma unroll
            for (int ji = 0; ji < 4; ++ji)
                acc[ri][ji] += hv.x * wv[ji].x + hv.y * wv[ji].y
                             + hv.z * wv[ji].z + hv.w * wv[ji].w;
        }
    }

    #pragma unroll
    for (int ri = 0; ri < 8; ++ri) {
        const int r = rg * 8 + ri;
        float z[4], ss = 0.f;
        #pragma unroll
        for (int ji = 0; ji < 4; ++ji) {
            z[ji] = 1.0f / (1.0f + __expf(-acc[ri][ji]));
            ss += z[ji] * z[ji];
        }
        #pragma unroll
        for (int m = 16; m >= 1; m >>= 1)
            ss += __shfl_xor(ss, m, 32);
        const float rn = rsqrtf(ss);
        if (r < rows) {
            float4 o; o.x = z[0] * rn; o.y = z[1] * rn; o.z = z[2] * rn; o.w = z[3] * rn;
            *(float4*)(out + (size_t)(base + r) * D + j0) = o;
        }
    }
}

// ---------------- Fallback: R1's fused kernel verbatim (passed both checks) ----------------
__global__ __launch_bounds__(BLOCK, 2) void sage_fused_kernel(
    const int* __restrict__ batch, const int* __restrict__ neigh,
    const float* __restrict__ Z, const float* __restrict__ W,
    float* __restrict__ out, int B)
{
    __shared__ float Hs[ROWS * HS];
    __shared__ int   sb[ROWS];
    __shared__ int   sn[ROWS * S];

    const int tid  = threadIdx.x;
    const int base = blockIdx.x * ROWS;
    const int rows = min(ROWS, B - base);

    for (int x = tid; x < rows; x += BLOCK)     sb[x] = batch[base + x];
    for (int x = tid; x < rows * S; x += BLOCK) sn[x] = neigh[base * S + x];
    __syncthreads();

    #pragma unroll
    for (int w = 0; w < (ROWS * 32) / BLOCK; ++w) {
        const int task = w * BLOCK + tid;
        const int r = task >> 5;
        const int c = task & 31;
        if (r < rows) {
            const float4 sv = ((const float4*)(Z + (size_t)sb[r] * D))[c];
            float ax = 0.f, ay = 0.f, az = 0.f, aw = 0.f;
            #pragma unroll
            for (int s = 0; s < S; ++s) {
                const float4 v = ((const float4*)(Z + (size_t)sn[r * S + s] * D))[c];
                ax += v.x; ay += v.y; az += v.z; aw += v.w;
            }
            *(float4*)&Hs[r * HS + c * 4] = sv;
            float4 m; m.x = ax * 0.1f; m.y = ay * 0.1f; m.z = az * 0.1f; m.w = aw * 0.1f;
            *(float4*)&Hs[r * HS + D + c * 4] = m;
        } else {
            const float4 zz = {0.f, 0.f, 0.f, 0.f};
            *(float4*)&Hs[r * HS + c * 4]     = zz;
            *(float4*)&Hs[r * HS + D + c * 4] = zz;
        }
    }
    __syncthreads();

    const int jg = tid & 31;
    const int rg = tid >> 5;
    const int j0 = jg * 4;

    float acc[8][4];
    #pragma unroll
    for (int i = 0; i < 8; ++i)
        #pragma unroll
        for (int j = 0; j < 4; ++j) acc[i][j] = 0.f;

    for (int k4 = 0; k4 < (2 * D) / 4; ++k4) {
        const int k = k4 * 4;
        float4 wv[4];
        #pragma unroll
        for (int ji = 0; ji < 4; ++ji)
            wv[ji] = *(const float4*)(W + (size_t)(j0 + ji) * (2 * D) + k);
        #pragma unroll
        for (int ri = 0; ri < 8; ++ri) {
            const float4 hv = *(const float4*)&Hs[(rg * 8 + ri) * HS + k];
            #pragma unroll
            for (int ji = 0; ji < 4; ++ji)
                acc[ri][ji] += hv.x * wv[ji].x + hv.y * wv[ji].y
                             + hv.z * wv[ji].z + hv.w * wv[ji].w;
        }
    }

    #pragma unroll
    for (int ri = 0; ri < 8; ++ri) {
        const int r = rg * 8 + ri;
        float z[4], ss = 0.f;
        #pragma unroll
        for (int ji = 0; ji < 4; ++ji) {
            z[ji] = 1.0f / (1.0f + __expf(-acc[ri][ji]));
            ss += z[ji] * z[ji];
        }
        #pragma unroll
        for (int m = 16; m >= 1; m >>= 1)
            ss += __shfl_xor(ss, m, 32);
        const float rn = rsqrtf(ss);
        if (r < rows) {
            float4 o; o.x = z[0] * rn; o.y = z[1] * rn; o.z = z[2] * rn; o.w = z[3] * rn;
            *(float4*)(out + (size_t)(base + r) * D + j0) = o;
        }
    }
}

extern "C" void kernel_launch(void* const* d_in, const int* in_sizes, int n_in,
                              void* d_out, int out_size, void* d_ws, size_t ws_size,
                              hipStream_t stream) {
    const int*   batch = (const int*)d_in[0];
    const int*   neigh = (const int*)d_in[1];
    const float* Z     = (const float*)d_in[2];
    const float* W     = (const float*)d_in[3];
    float*       out   = (float*)d_out;
    const int B = in_sizes[0];

    const size_t ws_needed = (size_t)B * D * sizeof(float);
    if (ws_size >= ws_needed) {
        float* ws = (float*)d_ws;
        const int g1 = (B * 32 + BLOCK - 1) / BLOCK;          // 12500
        hipLaunchKernelGGL(mean_kernel, dim3(g1), dim3(BLOCK), 0, stream,
                           neigh, Z, ws, B);
        const int g2 = (B + ROWS - 1) / ROWS;                 // 1563
        hipLaunchKernelGGL(sage_gemm_kernel, dim3(g2), dim3(BLOCK), 0, stream,
                           batch, Z, ws, W, out, B);
    } else {
        const int g = (B + ROWS - 1) / ROWS;
        hipLaunchKernelGGL(sage_fused_kernel, dim3(g), dim3(BLOCK), 0, stream,
                           batch, neigh, Z, W, out, B);
    }
}

// Round 5
// 159.607 us; speedup vs baseline: 2.0127x; 2.0127x over previous
//
#include <hip/hip_runtime.h>

#define D      128
#define S      10
#define BLOCK  256

typedef __attribute__((ext_vector_type(8))) short short8;   // 8 bf16 (4 VGPRs)
typedef __attribute__((ext_vector_type(4))) float f32x4;

__device__ __forceinline__ unsigned short f2bf(float x) {
    union { float f; unsigned u; } v; v.f = x;
    unsigned r = v.u + 0x7fffu + ((v.u >> 16) & 1u);        // RNE
    return (unsigned short)(r >> 16);
}

// ---------------- K0: W fp32 -> bf16 (128 x 256) ----------------
__global__ void wconv_kernel(const float* __restrict__ W, unsigned short* __restrict__ Wb)
{
    const int i = blockIdx.x * BLOCK + threadIdx.x;       // 32768 elems
    if (i < D * 2 * D) Wb[i] = f2bf(W[i]);
}

// ---------------- K1: gather self + mean(neigh) -> hws[B][256] bf16 ----------------
// One thread per (row, float4 chunk). 11 independent 16B gathers, no LDS, no barriers.
__global__ void gather_kernel(
    const int* __restrict__ batch, const int* __restrict__ neigh,
    const float* __restrict__ Z, unsigned short* __restrict__ hws, int B)
{
    const int t = blockIdx.x * BLOCK + threadIdx.x;
    if (t >= B * 32) return;
    const int r = t >> 5;
    const int c = t & 31;

    const float4 sv = ((const float4*)(Z + (size_t)batch[r] * D))[c];
    const int* nr = neigh + (size_t)r * S;
    float ax = 0.f, ay = 0.f, az = 0.f, aw = 0.f;
    #pragma unroll
    for (int s = 0; s < S; ++s) {
        const float4 v = ((const float4*)(Z + (size_t)nr[s] * D))[c];
        ax += v.x; ay += v.y; az += v.z; aw += v.w;
    }

    ushort4 s16; s16.x = f2bf(sv.x); s16.y = f2bf(sv.y); s16.z = f2bf(sv.z); s16.w = f2bf(sv.w);
    ushort4 m16; m16.x = f2bf(ax * 0.1f); m16.y = f2bf(ay * 0.1f);
                 m16.z = f2bf(az * 0.1f); m16.w = f2bf(aw * 0.1f);
    *(ushort4*)(hws + (size_t)r * 256 + c * 4)       = s16;   // self  [0..127]
    *(ushort4*)(hws + (size_t)r * 256 + 128 + c * 4) = m16;   // mean  [128..255]
}

// ---------------- K2: streaming bf16 MFMA GEMM + sigmoid + L2-norm ----------------
// 64 rows/block, 4 waves; wave w owns rows w*16..w*16+15 (16x16x32 MFMA, 8 col-tiles).
#define KROWS 64
#define HPAD  264          // LDS row stride in shorts (256+8): 2-way bank aliasing only
__global__ __launch_bounds__(BLOCK, 4) void gemm_kernel(
    const unsigned short* __restrict__ hws, const unsigned short* __restrict__ Wb,
    float* __restrict__ out, int B)
{
    __shared__ short Hs[KROWS * HPAD];    // 33,792 B

    const int tid  = threadIdx.x;
    const int base = blockIdx.x * KROWS;
    const int rows = min(KROWS, B - base);

    // stage h tile (coalesced 16B chunks)
    #pragma unroll
    for (int it = 0; it < (KROWS * 32) / BLOCK; ++it) {   // 8 iters
        const int x   = it * BLOCK + tid;
        const int row = x >> 5;
        const int cc  = x & 31;
        uint4 v = {0u, 0u, 0u, 0u};
        if (row < rows)
            v = *(const uint4*)(hws + (size_t)(base + row) * 256 + cc * 8);
        *(uint4*)&Hs[row * HPAD + cc * 8] = v;
    }
    __syncthreads();

    const int l  = tid & 63;              // lane
    const int w  = tid >> 6;              // wave -> row tile
    const int m0 = w * 16;
    const int lr = l & 15;                // row (A) / col (B,D) within tile
    const int lg = l >> 4;                // k-group

    // preload A fragments for all 8 k-steps (lane: row m0+lr, k = ks*32 + lg*8 .. +7)
    short8 afr[8];
    #pragma unroll
    for (int ks = 0; ks < 8; ++ks)
        afr[ks] = *(const short8*)&Hs[(m0 + lr) * HPAD + ks * 32 + lg * 8];

    float zbuf[8][4];
    float ss[4] = {0.f, 0.f, 0.f, 0.f};

    #pragma unroll
    for (int jt = 0; jt < 8; ++jt) {
        f32x4 acc = {0.f, 0.f, 0.f, 0.f};
        #pragma unroll
        for (int ks = 0; ks < 8; ++ks) {
            // B[k][n] = W[j = jt*16+lr][k = ks*32 + lg*8 + i] : 16B contiguous per lane
            const short8 bfr = *(const short8*)(Wb + (size_t)(jt * 16 + lr) * 256 + ks * 32 + lg * 8);
            acc = __builtin_amdgcn_mfma_f32_16x16x32_bf16(afr[ks], bfr, acc, 0, 0, 0);
        }
        #pragma unroll
        for (int r = 0; r < 4; ++r) {     // D: row = lg*4+r, col = jt*16+lr
            const float z = 1.0f / (1.0f + __expf(-acc[r]));
            zbuf[jt][r] = z;
            ss[r] += z * z;
        }
    }

    // row sum-of-squares: reduce across the 16 lanes sharing lg (xor 1,2,4,8)
    #pragma unroll
    for (int r = 0; r < 4; ++r) {
        float s = ss[r];
        s += __shfl_xor(s, 1, 64);
        s += __shfl_xor(s, 2, 64);
        s += __shfl_xor(s, 4, 64);
        s += __shfl_xor(s, 8, 64);
        ss[r] = s;
    }

    #pragma unroll
    for (int r = 0; r < 4; ++r) {
        const int row = m0 + lg * 4 + r;
        if (row < rows) {
            const float rn = rsqrtf(ss[r]);
            #pragma unroll
            for (int jt = 0; jt < 8; ++jt)
                out[(size_t)(base + row) * D + jt * 16 + lr] = zbuf[jt][r] * rn;
        }
    }
}

// ---------------- Fallback: R1's fused kernel (passed both checks) ----------------
#define ROWS   64
#define HS     260
__global__ __launch_bounds__(BLOCK, 2) void sage_fused_kernel(
    const int* __restrict__ batch, const int* __restrict__ neigh,
    const float* __restrict__ Z, const float* __restrict__ W,
    float* __restrict__ out, int B)
{
    __shared__ float Hs[ROWS * HS];
    __shared__ int   sb[ROWS];
    __shared__ int   sn[ROWS * S];

    const int tid  = threadIdx.x;
    const int base = blockIdx.x * ROWS;
    const int rows = min(ROWS, B - base);

    for (int x = tid; x < rows; x += BLOCK)     sb[x] = batch[base + x];
    for (int x = tid; x < rows * S; x += BLOCK) sn[x] = neigh[base * S + x];
    __syncthreads();

    #pragma unroll
    for (int wv = 0; wv < (ROWS * 32) / BLOCK; ++wv) {
        const int task = wv * BLOCK + tid;
        const int r = task >> 5;
        const int c = task & 31;
        if (r < rows) {
            const float4 sv = ((const float4*)(Z + (size_t)sb[r] * D))[c];
            float ax = 0.f, ay = 0.f, az = 0.f, aw = 0.f;
            #pragma unroll
            for (int s = 0; s < S; ++s) {
                const float4 v = ((const float4*)(Z + (size_t)sn[r * S + s] * D))[c];
                ax += v.x; ay += v.y; az += v.z; aw += v.w;
            }
            *(float4*)&Hs[r * HS + c * 4] = sv;
            float4 m; m.x = ax * 0.1f; m.y = ay * 0.1f; m.z = az * 0.1f; m.w = aw * 0.1f;
            *(float4*)&Hs[r * HS + D + c * 4] = m;
        } else {
            const float4 zz = {0.f, 0.f, 0.f, 0.f};
            *(float4*)&Hs[r * HS + c * 4]     = zz;
            *(float4*)&Hs[r * HS + D + c * 4] = zz;
        }
    }
    __syncthreads();

    const int jg = tid & 31;
    const int rg = tid >> 5;
    const int j0 = jg * 4;

    float acc[8][4];
    #pragma unroll
    for (int i = 0; i < 8; ++i)
        #pragma unroll
        for (int j = 0; j < 4; ++j) acc[i][j] = 0.f;

    for (int k4 = 0; k4 < (2 * D) / 4; ++k4) {
        const int k = k4 * 4;
        float4 wv[4];
        #pragma unroll
        for (int ji = 0; ji < 4; ++ji)
            wv[ji] = *(const float4*)(W + (size_t)(j0 + ji) * (2 * D) + k);
        #pragma unroll
        for (int ri = 0; ri < 8; ++ri) {
            const float4 hv = *(const float4*)&Hs[(rg * 8 + ri) * HS + k];
            #pragma unroll
            for (int ji = 0; ji < 4; ++ji)
                acc[ri][ji] += hv.x * wv[ji].x + hv.y * wv[ji].y
                             + hv.z * wv[ji].z + hv.w * wv[ji].w;
        }
    }

    #pragma unroll
    for (int ri = 0; ri < 8; ++ri) {
        const int r = rg * 8 + ri;
        float z[4], s2 = 0.f;
        #pragma unroll
        for (int ji = 0; ji < 4; ++ji) {
            z[ji] = 1.0f / (1.0f + __expf(-acc[ri][ji]));
            s2 += z[ji] * z[ji];
        }
        #pragma unroll
        for (int m = 16; m >= 1; m >>= 1)
            s2 += __shfl_xor(s2, m, 32);
        const float rn = rsqrtf(s2);
        if (r < rows) {
            float4 o; o.x = z[0] * rn; o.y = z[1] * rn; o.z = z[2] * rn; o.w = z[3] * rn;
            *(float4*)(out + (size_t)(base + r) * D + j0) = o;
        }
    }
}

extern "C" void kernel_launch(void* const* d_in, const int* in_sizes, int n_in,
                              void* d_out, int out_size, void* d_ws, size_t ws_size,
                              hipStream_t stream) {
    const int*   batch = (const int*)d_in[0];
    const int*   neigh = (const int*)d_in[1];
    const float* Z     = (const float*)d_in[2];
    const float* W     = (const float*)d_in[3];
    float*       out   = (float*)d_out;
    const int B = in_sizes[0];

    const size_t h_bytes  = (size_t)B * 256 * sizeof(unsigned short); // bf16 [B][256]
    const size_t ws_needed = h_bytes + (size_t)D * 2 * D * sizeof(unsigned short);

    if (ws_size >= ws_needed) {
        unsigned short* hws = (unsigned short*)d_ws;
        unsigned short* Wb  = (unsigned short*)((char*)d_ws + h_bytes);

        hipLaunchKernelGGL(wconv_kernel, dim3((D * 2 * D + BLOCK - 1) / BLOCK), dim3(BLOCK),
                           0, stream, W, Wb);
        hipLaunchKernelGGL(gather_kernel, dim3((B * 32 + BLOCK - 1) / BLOCK), dim3(BLOCK),
                           0, stream, batch, neigh, Z, hws, B);
        hipLaunchKernelGGL(gemm_kernel, dim3((B + KROWS - 1) / KROWS), dim3(BLOCK),
                           0, stream, hws, Wb, out, B);
    } else {
        hipLaunchKernelGGL(sage_fused_kernel, dim3((B + ROWS - 1) / ROWS), dim3(BLOCK),
                           0, stream, batch, neigh, Z, W, out, B);
    }
}

// Round 6
// 124.113 us; speedup vs baseline: 2.5882x; 1.2860x over previous
//
#include <hip/hip_runtime.h>

#define D      128
#define S      10
#define BLOCK  256
#define KROWS  64
#define HPAD   264          // LDS row stride in shorts (256+8)

typedef __attribute__((ext_vector_type(8))) short short8;   // 8 bf16 (4 VGPRs)
typedef __attribute__((ext_vector_type(4))) float f32x4;

__device__ __forceinline__ unsigned short f2bf(float x) {
    union { float f; unsigned u; } v; v.f = x;
    unsigned r = v.u + 0x7fffu + ((v.u >> 16) & 1u);        // RNE
    return (unsigned short)(r >> 16);
}

// ---------------- K0: W fp32 -> bf16 (128 x 256) ----------------
__global__ void wconv_kernel(const float* __restrict__ W, unsigned short* __restrict__ Wb)
{
    const int i = blockIdx.x * BLOCK + threadIdx.x;
    if (i < D * 2 * D) Wb[i] = f2bf(W[i]);
}

// ---------------- Fused: gather -> bf16 LDS -> MFMA GEMM -> sigmoid -> L2-norm ----------------
// GEMM phase is R5-K2 verbatim (proven): wave w owns rows w*16..w*16+15, 8 col-tiles.
__global__ __launch_bounds__(BLOCK, 4) void sage_kernel(
    const int* __restrict__ batch, const int* __restrict__ neigh,
    const float* __restrict__ Z, const unsigned short* __restrict__ Wb,
    float* __restrict__ out, int B)
{
    __shared__ short Hs[KROWS * HPAD];    // 33,792 B
    __shared__ int   sb[KROWS];
    __shared__ int   sn[KROWS * S];

    const int tid  = threadIdx.x;
    const int base = blockIdx.x * KROWS;
    const int rows = min(KROWS, B - base);

    // ---- stage indices ----
    for (int x = tid; x < rows; x += BLOCK)     sb[x] = batch[base + x];
    for (int x = tid; x < rows * S; x += BLOCK) sn[x] = neigh[base * S + x];
    __syncthreads();

    // ---- gather + mean + bf16 convert, straight into Hs ----
    #pragma unroll
    for (int it = 0; it < (KROWS * 32) / BLOCK; ++it) {   // 8 iterations
        const int task = it * BLOCK + tid;
        const int r = task >> 5;
        const int c = task & 31;
        if (r < rows) {
            const float4 sv = ((const float4*)(Z + (size_t)sb[r] * D))[c];
            float ax = 0.f, ay = 0.f, az = 0.f, aw = 0.f;
            #pragma unroll
            for (int s = 0; s < S; ++s) {
                const float4 v = ((const float4*)(Z + (size_t)sn[r * S + s] * D))[c];
                ax += v.x; ay += v.y; az += v.z; aw += v.w;
            }
            ushort4 s16; s16.x = f2bf(sv.x); s16.y = f2bf(sv.y);
                         s16.z = f2bf(sv.z); s16.w = f2bf(sv.w);
            ushort4 m16; m16.x = f2bf(ax * 0.1f); m16.y = f2bf(ay * 0.1f);
                         m16.z = f2bf(az * 0.1f); m16.w = f2bf(aw * 0.1f);
            *(ushort4*)&Hs[r * HPAD + c * 4]       = s16;   // self  [0..127]
            *(ushort4*)&Hs[r * HPAD + 128 + c * 4] = m16;   // mean  [128..255]
        } else {
            const ushort4 zz = {0, 0, 0, 0};
            *(ushort4*)&Hs[r * HPAD + c * 4]       = zz;
            *(ushort4*)&Hs[r * HPAD + 128 + c * 4] = zz;
        }
    }
    __syncthreads();

    // ---- MFMA GEMM (R5-K2 structure) ----
    const int l  = tid & 63;
    const int w  = tid >> 6;
    const int m0 = w * 16;
    const int lr = l & 15;                // A row / B,D col within tile
    const int lg = l >> 4;                // k-group

    short8 afr[8];
    #pragma unroll
    for (int ks = 0; ks < 8; ++ks)
        afr[ks] = *(const short8*)&Hs[(m0 + lr) * HPAD + ks * 32 + lg * 8];

    float zbuf[8][4];
    float ss[4] = {0.f, 0.f, 0.f, 0.f};

    #pragma unroll
    for (int jt = 0; jt < 8; ++jt) {
        f32x4 acc = {0.f, 0.f, 0.f, 0.f};
        #pragma unroll
        for (int ks = 0; ks < 8; ++ks) {
            const short8 bfr = *(const short8*)(Wb + (size_t)(jt * 16 + lr) * 256 + ks * 32 + lg * 8);
            acc = __builtin_amdgcn_mfma_f32_16x16x32_bf16(afr[ks], bfr, acc, 0, 0, 0);
        }
        #pragma unroll
        for (int r = 0; r < 4; ++r) {     // D: row = m0 + lg*4 + r, col = jt*16 + lr
            const float z = 1.0f / (1.0f + __expf(-acc[r]));
            zbuf[jt][r] = z;
            ss[r] += z * z;
        }
    }

    #pragma unroll
    for (int r = 0; r < 4; ++r) {
        float s = ss[r];
        s += __shfl_xor(s, 1, 64);
        s += __shfl_xor(s, 2, 64);
        s += __shfl_xor(s, 4, 64);
        s += __shfl_xor(s, 8, 64);
        ss[r] = s;
    }

    #pragma unroll
    for (int r = 0; r < 4; ++r) {
        const int row = m0 + lg * 4 + r;
        if (row < rows) {
            const float rn = rsqrtf(ss[r]);
            #pragma unroll
            for (int jt = 0; jt < 8; ++jt)
                out[(size_t)(base + row) * D + jt * 16 + lr] = zbuf[jt][r] * rn;
        }
    }
}

// ---------------- Fallback: R1's fused fp32 kernel (proven) ----------------
#define ROWS   64
#define HS     260
__global__ __launch_bounds__(BLOCK, 2) void sage_fused_kernel(
    const int* __restrict__ batch, const int* __restrict__ neigh,
    const float* __restrict__ Z, const float* __restrict__ W,
    float* __restrict__ out, int B)
{
    __shared__ float Hs[ROWS * HS];
    __shared__ int   sb[ROWS];
    __shared__ int   sn[ROWS * S];

    const int tid  = threadIdx.x;
    const int base = blockIdx.x * ROWS;
    const int rows = min(ROWS, B - base);

    for (int x = tid; x < rows; x += BLOCK)     sb[x] = batch[base + x];
    for (int x = tid; x < rows * S; x += BLOCK) sn[x] = neigh[base * S + x];
    __syncthreads();

    #pragma unroll
    for (int wv = 0; wv < (ROWS * 32) / BLOCK; ++wv) {
        const int task = wv * BLOCK + tid;
        const int r = task >> 5;
        const int c = task & 31;
        if (r < rows) {
            const float4 sv = ((const float4*)(Z + (size_t)sb[r] * D))[c];
            float ax = 0.f, ay = 0.f, az = 0.f, aw = 0.f;
            #pragma unroll
            for (int s = 0; s < S; ++s) {
                const float4 v = ((const float4*)(Z + (size_t)sn[r * S + s] * D))[c];
                ax += v.x; ay += v.y; az += v.z; aw += v.w;
            }
            *(float4*)&Hs[r * HS + c * 4] = sv;
            float4 m; m.x = ax * 0.1f; m.y = ay * 0.1f; m.z = az * 0.1f; m.w = aw * 0.1f;
            *(float4*)&Hs[r * HS + D + c * 4] = m;
        } else {
            const float4 zz = {0.f, 0.f, 0.f, 0.f};
            *(float4*)&Hs[r * HS + c * 4]     = zz;
            *(float4*)&Hs[r * HS + D + c * 4] = zz;
        }
    }
    __syncthreads();

    const int jg = tid & 31;
    const int rg = tid >> 5;
    const int j0 = jg * 4;

    float acc[8][4];
    #pragma unroll
    for (int i = 0; i < 8; ++i)
        #pragma unroll
        for (int j = 0; j < 4; ++j) acc[i][j] = 0.f;

    for (int k4 = 0; k4 < (2 * D) / 4; ++k4) {
        const int k = k4 * 4;
        float4 wv[4];
        #pragma unroll
        for (int ji = 0; ji < 4; ++ji)
            wv[ji] = *(const float4*)(W + (size_t)(j0 + ji) * (2 * D) + k);
        #pragma unroll
        for (int ri = 0; ri < 8; ++ri) {
            const float4 hv = *(const float4*)&Hs[(rg * 8 + ri) * HS + k];
            #pragma unroll
            for (int ji = 0; ji < 4; ++ji)
                acc[ri][ji] += hv.x * wv[ji].x + hv.y * wv[ji].y
                             + hv.z * wv[ji].z + hv.w * wv[ji].w;
        }
    }

    #pragma unroll
    for (int ri = 0; ri < 8; ++ri) {
        const int r = rg * 8 + ri;
        float z[4], s2 = 0.f;
        #pragma unroll
        for (int ji = 0; ji < 4; ++ji) {
            z[ji] = 1.0f / (1.0f + __expf(-acc[ri][ji]));
            s2 += z[ji] * z[ji];
        }
        #pragma unroll
        for (int m = 16; m >= 1; m >>= 1)
            s2 += __shfl_xor(s2, m, 32);
        const float rn = rsqrtf(s2);
        if (r < rows) {
            float4 o; o.x = z[0] * rn; o.y = z[1] * rn; o.z = z[2] * rn; o.w = z[3] * rn;
            *(float4*)(out + (size_t)(base + r) * D + j0) = o;
        }
    }
}

extern "C" void kernel_launch(void* const* d_in, const int* in_sizes, int n_in,
                              void* d_out, int out_size, void* d_ws, size_t ws_size,
                              hipStream_t stream) {
    const int*   batch = (const int*)d_in[0];
    const int*   neigh = (const int*)d_in[1];
    const float* Z     = (const float*)d_in[2];
    const float* W     = (const float*)d_in[3];
    float*       out   = (float*)d_out;
    const int B = in_sizes[0];

    const size_t wb_bytes = (size_t)D * 2 * D * sizeof(unsigned short);   // 64 KB

    if (ws_size >= wb_bytes) {
        unsigned short* Wb = (unsigned short*)d_ws;
        hipLaunchKernelGGL(wconv_kernel, dim3((D * 2 * D + BLOCK - 1) / BLOCK), dim3(BLOCK),
                           0, stream, W, Wb);
        hipLaunchKernelGGL(sage_kernel, dim3((B + KROWS - 1) / KROWS), dim3(BLOCK),
                           0, stream, batch, neigh, Z, Wb, out, B);
    } else {
        hipLaunchKernelGGL(sage_fused_kernel, dim3((B + ROWS - 1) / ROWS), dim3(BLOCK),
                           0, stream, batch, neigh, Z, W, out, B);
    }
}

// Round 7
// 123.218 us; speedup vs baseline: 2.6070x; 1.0073x over previous
//
#include <hip/hip_runtime.h>

#define D      128
#define S      10
#define BLOCK  128
#define KROWS  32
#define HPAD   264          // LDS row stride in shorts (256+8)

typedef __attribute__((ext_vector_type(8))) short short8;   // 8 bf16 (4 VGPRs)
typedef __attribute__((ext_vector_type(4))) float f32x4;

__device__ __forceinline__ unsigned short f2bf(float x) {
    union { float f; unsigned u; } v; v.f = x;
    unsigned r = v.u + 0x7fffu + ((v.u >> 16) & 1u);        // RNE
    return (unsigned short)(r >> 16);
}

// ---------------- K0: W fp32 -> bf16 (128 x 256) ----------------
__global__ void wconv_kernel(const float* __restrict__ W, unsigned short* __restrict__ Wb)
{
    const int i = blockIdx.x * 256 + threadIdx.x;
    if (i < D * 2 * D) Wb[i] = f2bf(W[i]);
}

// ---------------- Fused: gather -> bf16 LDS -> MFMA GEMM -> sigmoid -> L2-norm ----------------
// 32 rows/block, 2 waves; wave w owns rows w*16..w*16+15 (16x16x32 MFMA, 8 col-tiles).
// GEMM/reduce/store logic identical to the R5/R6 proven structure.
__global__ __launch_bounds__(BLOCK, 4) void sage_kernel(
    const int* __restrict__ batch, const int* __restrict__ neigh,
    const float* __restrict__ Z, const unsigned short* __restrict__ Wb,
    float* __restrict__ out, int B)
{
    __shared__ short Hs[KROWS * HPAD];    // 16,896 B
    __shared__ int   sb[KROWS];
    __shared__ int   sn[KROWS * S];

    const int tid  = threadIdx.x;
    const int base = blockIdx.x * KROWS;
    const int rows = min(KROWS, B - base);

    // ---- stage indices ----
    for (int x = tid; x < rows; x += BLOCK)     sb[x] = batch[base + x];
    for (int x = tid; x < rows * S; x += BLOCK) sn[x] = neigh[base * S + x];
    __syncthreads();

    // ---- gather + mean + bf16 convert, straight into Hs ----
    #pragma unroll
    for (int it = 0; it < (KROWS * 32) / BLOCK; ++it) {   // 8 iterations
        const int task = it * BLOCK + tid;
        const int r = task >> 5;
        const int c = task & 31;
        if (r < rows) {
            const float4 sv = ((const float4*)(Z + (size_t)sb[r] * D))[c];
            float ax = 0.f, ay = 0.f, az = 0.f, aw = 0.f;
            #pragma unroll
            for (int s = 0; s < S; ++s) {
                const float4 v = ((const float4*)(Z + (size_t)sn[r * S + s] * D))[c];
                ax += v.x; ay += v.y; az += v.z; aw += v.w;
            }
            ushort4 s16; s16.x = f2bf(sv.x); s16.y = f2bf(sv.y);
                         s16.z = f2bf(sv.z); s16.w = f2bf(sv.w);
            ushort4 m16; m16.x = f2bf(ax * 0.1f); m16.y = f2bf(ay * 0.1f);
                         m16.z = f2bf(az * 0.1f); m16.w = f2bf(aw * 0.1f);
            *(ushort4*)&Hs[r * HPAD + c * 4]       = s16;   // self  [0..127]
            *(ushort4*)&Hs[r * HPAD + 128 + c * 4] = m16;   // mean  [128..255]
        } else {
            const ushort4 zz = {0, 0, 0, 0};
            *(ushort4*)&Hs[r * HPAD + c * 4]       = zz;
            *(ushort4*)&Hs[r * HPAD + 128 + c * 4] = zz;
        }
    }
    __syncthreads();

    // ---- MFMA GEMM ----
    const int l  = tid & 63;
    const int w  = tid >> 6;              // 0..1
    const int m0 = w * 16;
    const int lr = l & 15;                // A row / B,D col within tile
    const int lg = l >> 4;                // k-group

    short8 afr[8];
    #pragma unroll
    for (int ks = 0; ks < 8; ++ks)
        afr[ks] = *(const short8*)&Hs[(m0 + lr) * HPAD + ks * 32 + lg * 8];

    float zbuf[8][4];
    float ss[4] = {0.f, 0.f, 0.f, 0.f};

    #pragma unroll
    for (int jt = 0; jt < 8; ++jt) {
        f32x4 acc = {0.f, 0.f, 0.f, 0.f};
        #pragma unroll
        for (int ks = 0; ks < 8; ++ks) {
            const short8 bfr = *(const short8*)(Wb + (size_t)(jt * 16 + lr) * 256 + ks * 32 + lg * 8);
            acc = __builtin_amdgcn_mfma_f32_16x16x32_bf16(afr[ks], bfr, acc, 0, 0, 0);
        }
        #pragma unroll
        for (int r = 0; r < 4; ++r) {     // D: row = m0 + lg*4 + r, col = jt*16 + lr
            const float z = 1.0f / (1.0f + __expf(-acc[r]));
            zbuf[jt][r] = z;
            ss[r] += z * z;
        }
    }

    #pragma unroll
    for (int r = 0; r < 4; ++r) {
        float s = ss[r];
        s += __shfl_xor(s, 1, 64);
        s += __shfl_xor(s, 2, 64);
        s += __shfl_xor(s, 4, 64);
        s += __shfl_xor(s, 8, 64);
        ss[r] = s;
    }

    #pragma unroll
    for (int r = 0; r < 4; ++r) {
        const int row = m0 + lg * 4 + r;
        if (row < rows) {
            const float rn = rsqrtf(ss[r]);
            #pragma unroll
            for (int jt = 0; jt < 8; ++jt)
                out[(size_t)(base + row) * D + jt * 16 + lr] = zbuf[jt][r] * rn;
        }
    }
}

// ---------------- Fallback: R1's fused fp32 kernel (proven) ----------------
#define ROWS   64
#define HS     260
#define FBLOCK 256
__global__ __launch_bounds__(FBLOCK, 2) void sage_fused_kernel(
    const int* __restrict__ batch, const int* __restrict__ neigh,
    const float* __restrict__ Z, const float* __restrict__ W,
    float* __restrict__ out, int B)
{
    __shared__ float Hs[ROWS * HS];
    __shared__ int   sb[ROWS];
    __shared__ int   sn[ROWS * S];

    const int tid  = threadIdx.x;
    const int base = blockIdx.x * ROWS;
    const int rows = min(ROWS, B - base);

    for (int x = tid; x < rows; x += FBLOCK)     sb[x] = batch[base + x];
    for (int x = tid; x < rows * S; x += FBLOCK) sn[x] = neigh[base * S + x];
    __syncthreads();

    #pragma unroll
    for (int wv = 0; wv < (ROWS * 32) / FBLOCK; ++wv) {
        const int task = wv * FBLOCK + tid;
        const int r = task >> 5;
        const int c = task & 31;
        if (r < rows) {
            const float4 sv = ((const float4*)(Z + (size_t)sb[r] * D))[c];
            float ax = 0.f, ay = 0.f, az = 0.f, aw = 0.f;
            #pragma unroll
            for (int s = 0; s < S; ++s) {
                const float4 v = ((const float4*)(Z + (size_t)sn[r * S + s] * D))[c];
                ax += v.x; ay += v.y; az += v.z; aw += v.w;
            }
            *(float4*)&Hs[r * HS + c * 4] = sv;
            float4 m; m.x = ax * 0.1f; m.y = ay * 0.1f; m.z = az * 0.1f; m.w = aw * 0.1f;
            *(float4*)&Hs[r * HS + D + c * 4] = m;
        } else {
            const float4 zz = {0.f, 0.f, 0.f, 0.f};
            *(float4*)&Hs[r * HS + c * 4]     = zz;
            *(float4*)&Hs[r * HS + D + c * 4] = zz;
        }
    }
    __syncthreads();

    const int jg = tid & 31;
    const int rg = tid >> 5;
    const int j0 = jg * 4;

    float acc[8][4];
    #pragma unroll
    for (int i = 0; i < 8; ++i)
        #pragma unroll
        for (int j = 0; j < 4; ++j) acc[i][j] = 0.f;

    for (int k4 = 0; k4 < (2 * D) / 4; ++k4) {
        const int k = k4 * 4;
        float4 wv[4];
        #pragma unroll
        for (int ji = 0; ji < 4; ++ji)
            wv[ji] = *(const float4*)(W + (size_t)(j0 + ji) * (2 * D) + k);
        #pragma unroll
        for (int ri = 0; ri < 8; ++ri) {
            const float4 hv = *(const float4*)&Hs[(rg * 8 + ri) * HS + k];
            #pragma unroll
            for (int ji = 0; ji < 4; ++ji)
                acc[ri][ji] += hv.x * wv[ji].x + hv.y * wv[ji].y
                             + hv.z * wv[ji].z + hv.w * wv[ji].w;
        }
    }

    #pragma unroll
    for (int ri = 0; ri < 8; ++ri) {
        const int r = rg * 8 + ri;
        float z[4], s2 = 0.f;
        #pragma unroll
        for (int ji = 0; ji < 4; ++ji) {
            z[ji] = 1.0f / (1.0f + __expf(-acc[ri][ji]));
            s2 += z[ji] * z[ji];
        }
        #pragma unroll
        for (int m = 16; m >= 1; m >>= 1)
            s2 += __shfl_xor(s2, m, 32);
        const float rn = rsqrtf(s2);
        if (r < rows) {
            float4 o; o.x = z[0] * rn; o.y = z[1] * rn; o.z = z[2] * rn; o.w = z[3] * rn;
            *(float4*)(out + (size_t)(base + r) * D + j0) = o;
        }
    }
}

extern "C" void kernel_launch(void* const* d_in, const int* in_sizes, int n_in,
                              void* d_out, int out_size, void* d_ws, size_t ws_size,
                              hipStream_t stream) {
    const int*   batch = (const int*)d_in[0];
    const int*   neigh = (const int*)d_in[1];
    const float* Z     = (const float*)d_in[2];
    const float* W     = (const float*)d_in[3];
    float*       out   = (float*)d_out;
    const int B = in_sizes[0];

    const size_t wb_bytes = (size_t)D * 2 * D * sizeof(unsigned short);   // 64 KB

    if (ws_size >= wb_bytes) {
        unsigned short* Wb = (unsigned short*)d_ws;
        hipLaunchKernelGGL(wconv_kernel, dim3((D * 2 * D + 255) / 256), dim3(256),
                           0, stream, W, Wb);
        hipLaunchKernelGGL(sage_kernel, dim3((B + KROWS - 1) / KROWS), dim3(BLOCK),
                           0, stream, batch, neigh, Z, Wb, out, B);
    } else {
        hipLaunchKernelGGL(sage_fused_kernel, dim3((B + ROWS - 1) / ROWS), dim3(FBLOCK),
                           0, stream, batch, neigh, Z, W, out, B);
    }
}